// Round 1
// baseline (2832.177 us; speedup 1.0000x reference)
//
#include <hip/hip_runtime.h>

#define SEQ    59
#define FEAT   64
#define VOCAB  578
#define BATCH  4096
#define UNITS  1024
#define KLSTM  1088   // FEAT + UNITS (real K)
#define KPAD   1152   // 18 K-tiles of 64; tile 17 is zero padding
#define HSTRIDE 1088  // h row stride: 1024 real + 64 zero pad
#define NPAD   640    // VOCAB padded to 5*128

typedef __bf16 bf16x8 __attribute__((ext_vector_type(8)));
typedef __bf16 bf16x4 __attribute__((ext_vector_type(4)));
typedef float  floatx4 __attribute__((ext_vector_type(4)));

typedef const __attribute__((address_space(1))) char gas_char;
typedef __attribute__((address_space(3))) char las_char;

__device__ __forceinline__ float sigmoid_f(float x) { return 1.f / (1.f + __expf(-x)); }
__device__ __forceinline__ float tanh_f(float x) { float e = __expf(2.f * x); return 1.f - 2.f / (e + 1.f); }

#define GLDS(srcp, dstp) __builtin_amdgcn_global_load_lds((gas_char*)(srcp), (las_char*)(dstp), 16, 0, 0)
#define BAR()  __builtin_amdgcn_s_barrier()
#define LGKM0() asm volatile("s_waitcnt lgkmcnt(0)" ::: "memory")
#define VM6()  asm volatile("s_waitcnt vmcnt(6)" ::: "memory")
#define MFMA   __builtin_amdgcn_mfma_f32_16x16x32_bf16

// ---------------- conversion kernels ----------------

__global__ void convert_x_kernel(const float* __restrict__ x, __bf16* __restrict__ xbf) {
    int i = blockIdx.x * 256 + threadIdx.x;
    const int total = BATCH * SEQ * FEAT / 4;
    if (i >= total) return;
    float4 v = ((const float4*)x)[i];
    bf16x4 o;
    o.x = (__bf16)v.x; o.y = (__bf16)v.y; o.z = (__bf16)v.z; o.w = (__bf16)v.w;
    ((bf16x4*)xbf)[i] = o;
}

// Wtp [4096 rows][KPAD k] bf16 row-major.
// row np = bc*256 + w*64 + g*16 + j  ->  gate g of unit u = bc*64 + w*16 + j
// (each wave's 64 cols hold all 4 gates of its 16 units)
__global__ void convert_weights_kernel(const float* __restrict__ kern,
                                       const float* __restrict__ reck,
                                       __bf16* __restrict__ Wtp) {
    int idx = blockIdx.x * 256 + threadIdx.x;
    if (idx >= 4096 * KPAD) return;
    int np = idx / KPAD;
    int k  = idx - np * KPAD;
    int bc = np >> 8;
    int w  = (np >> 6) & 3;
    int g  = (np >> 4) & 3;
    int j  = np & 15;
    int n  = g * 1024 + bc * 64 + w * 16 + j;
    float v = 0.f;
    if (k < FEAT)       v = kern[(size_t)k * 4096 + n];
    else if (k < KLSTM) v = reck[(size_t)(k - FEAT) * 4096 + n];
    Wtp[idx] = (__bf16)v;
}

__global__ void convert_w2_kernel(const float* __restrict__ w2, __bf16* __restrict__ Wt2p) {
    int idx = blockIdx.x * 256 + threadIdx.x;
    if (idx >= NPAD * 1024) return;
    int n = idx >> 10;
    int k = idx & 1023;
    float v = (n < VOCAB) ? w2[(size_t)k * VOCAB + n] : 0.f;
    Wt2p[idx] = (__bf16)v;
}

// ---------------- LSTM step: 256x256 tile, 8 waves, 8-phase counted-vmcnt ----------------
// Tile t (K-tile of 64) lives in buf[t&1]. Iter i computes tiles 2i (buf0, P0-P3)
// and 2i+1 (buf1, P4-P7). One half-tile (16KB, 2 loads/thread) staged per phase:
//   P0: A.kh1(2i+1)->buf1   P1: B.nh1(2i+2)->buf0  P2: A.kh0(2i+2)->buf0  P3: B.nh0(2i+2)->buf0
//   P4: A.kh1(2i+2)->buf0   P5: B.nh1(2i+3)->buf1  P6: A.kh0(2i+3)->buf1  P7: B.nh0(2i+3)->buf1
// vmcnt(6) at end of P3/P7 (3 half-tiles in flight) guarantees: stage@<=P0 readable from P4,
// stage@<=P4 readable from next P0. All b-frags of a tile read at its first phase (q0);
// A.kh0 read q0/q1, A.kh1 read q2/q3 -> every region free >=1 phase before its re-stage.
__global__ void __launch_bounds__(512, 2) lstm_step_kernel(
    const __bf16* __restrict__ xbf,
    const __bf16* __restrict__ Wtp,
    const float*  __restrict__ bias,
    const __bf16* __restrict__ hin,
    __bf16*       __restrict__ hout,
    float*        __restrict__ cstate,
    int t)
{
    __shared__ __bf16 Ash[2][2][256 * 32];  // [buf][kh]  64 KiB
    __shared__ __bf16 Bsh[2][2][128 * 64];  // [buf][nh]  64 KiB

    const int tid  = threadIdx.x;
    const int wid  = tid >> 6;
    const int lane = tid & 63;
    const int ln   = lane & 15;
    const int lk   = lane >> 4;
    const int wm   = wid >> 2;      // 0..1 (row half)
    const int wn   = wid & 3;       // 0..3 (col quarter)
    const int rb   = blockIdx.x;    // batch block (256 rows)
    const int bc   = blockIdx.y;    // unit block (64 units = 256 gate-cols)

    floatx4 acc[8][4];
#pragma unroll
    for (int m = 0; m < 8; ++m)
#pragma unroll
        for (int g = 0; g < 4; ++g)
            acc[m][g] = (floatx4){0.f, 0.f, 0.f, 0.f};

    // ---- stage slot mapping (per thread, 2 rounds) ----
    // A half-tile: 256 rows x 32 k; slot flat=q*512+tid: row=flat>>2, chunk c=flat&3,
    //   source chunk cg = c ^ ((row>>1)&3)  (involution; read applies same XOR)
    const int af0 = tid, af1 = 512 + tid;
    const int ar0 = af0 >> 2, ar1 = af1 >> 2;
    const int ac0 = (af0 & 3) ^ ((ar0 >> 1) & 3);
    const int ac1 = (af1 & 3) ^ ((ar1 >> 1) & 3);
    // B half-tile: 128 rows x 64 k; row=flat>>3, chunk=flat&7, cg = c ^ (row&7)
    const int br0 = af0 >> 3, br1 = af1 >> 3;
    const int bc0 = (af0 & 7) ^ (br0 & 7);
    const int bc1 = (af1 & 7) ^ (br1 & 7);

    const __bf16* hA0 = hin + (size_t)(rb * 256 + ar0) * HSTRIDE + ac0 * 8;
    const __bf16* hA1 = hin + (size_t)(rb * 256 + ar1) * HSTRIDE + ac1 * 8;
    const __bf16* xA0 = xbf + (size_t)(rb * 256 + ar0) * (SEQ * FEAT) + t * FEAT + ac0 * 8;
    const __bf16* xA1 = xbf + (size_t)(rb * 256 + ar1) * (SEQ * FEAT) + t * FEAT + ac1 * 8;
    const __bf16* wB0 = Wtp + (size_t)(bc * 256 + br0) * KPAD + bc0 * 8;
    const __bf16* wB1 = Wtp + (size_t)(bc * 256 + br1) * KPAD + bc1 * 8;

    const int adst0 = (wid << 9);          // (0*512 + wid*64)*8 elems
    const int adst1 = 4096 + (wid << 9);   // (1*512 + wid*64)*8 elems

#define STA(BUF, KH, COLB) do { \
    GLDS(hA0 + (COLB) + (KH) * 32, &Ash[BUF][KH][adst0]); \
    GLDS(hA1 + (COLB) + (KH) * 32, &Ash[BUF][KH][adst1]); } while (0)
#define STB(BUF, NH, COLB) do { \
    GLDS(wB0 + (size_t)(NH) * 128 * KPAD + (COLB), &Bsh[BUF][NH][adst0]); \
    GLDS(wB1 + (size_t)(NH) * 128 * KPAD + (COLB), &Bsh[BUF][NH][adst1]); } while (0)

    // ---- read offsets (elements) ----
    int offA[8];
#pragma unroll
    for (int m = 0; m < 8; ++m) {
        int row = wm * 128 + m * 16 + ln;
        offA[m] = row * 32 + ((lk ^ ((row >> 1) & 3)) << 3);
    }
    int offB[4][2];
#pragma unroll
    for (int g = 0; g < 4; ++g) {
        int nr = (wn & 1) * 64 + g * 16 + ln;
#pragma unroll
        for (int kk = 0; kk < 2; ++kk)
            offB[g][kk] = nr * 64 + ((((kk << 2) + lk) ^ (nr & 7)) << 3);
    }
    const int nhsel = wn >> 1;
    const __bf16* B0  = Bsh[0][nhsel];
    const __bf16* B1  = Bsh[1][nhsel];
    const __bf16* A00 = Ash[0][0];
    const __bf16* A01 = Ash[0][1];
    const __bf16* A10 = Ash[1][0];
    const __bf16* A11 = Ash[1][1];

    // ---- prologue: 7 half-tiles (tile0 full from x, tile1 except A.kh1) ----
    STB(0, 1, 0);
    GLDS(xA0, &Ash[0][0][adst0]); GLDS(xA1, &Ash[0][0][adst1]);
    STB(0, 0, 0);
    GLDS(xA0 + 32, &Ash[0][1][adst0]); GLDS(xA1 + 32, &Ash[0][1][adst1]);
    STB(1, 1, 64);
    STA(1, 0, 0);
    STB(1, 0, 64);
    VM6();
    BAR();

#define PHASE_MFMA(MB, KKB) \
    __builtin_amdgcn_s_setprio(1); \
    _Pragma("unroll") \
    for (int m = 0; m < 4; ++m) \
    _Pragma("unroll") \
        for (int g = 0; g < 4; ++g) \
            acc[(MB) + m][g] = MFMA(aa[m], bb[KKB][g], acc[(MB) + m][g], 0, 0, 0); \
    __builtin_amdgcn_s_setprio(0)

#pragma unroll 1
    for (int it = 0; it < 9; ++it) {
        const int t2 = (2 * it + 2 <= 17) ? (2 * it + 2) : 17;
        const int t3 = (2 * it + 3 <= 17) ? (2 * it + 3) : 17;
        const int cA1 = it * 128;           // (2i+1-1)*64
        const int cB2 = t2 * 64, cA2 = (t2 - 1) * 64;
        const int cB3 = t3 * 64, cA3 = (t3 - 1) * 64;
        bf16x8 bb[2][4], aa[4];

        // ---- even tile (buf0) ----
        // P0: q0 -- all b-frags + a kk0 m0-3
#pragma unroll
        for (int g = 0; g < 4; ++g) {
            bb[0][g] = *(const bf16x8*)(B0 + offB[g][0]);
            bb[1][g] = *(const bf16x8*)(B0 + offB[g][1]);
        }
#pragma unroll
        for (int m = 0; m < 4; ++m) aa[m] = *(const bf16x8*)(A00 + offA[m]);
        STA(1, 1, cA1);
        BAR(); LGKM0();
        PHASE_MFMA(0, 0);
        BAR();
        // P1: a kk0 m4-7
#pragma unroll
        for (int m = 0; m < 4; ++m) aa[m] = *(const bf16x8*)(A00 + offA[4 + m]);
        STB(0, 1, cB2);
        BAR(); LGKM0();
        PHASE_MFMA(4, 0);
        BAR();
        // P2: a kk1 m0-3
#pragma unroll
        for (int m = 0; m < 4; ++m) aa[m] = *(const bf16x8*)(A01 + offA[m]);
        STA(0, 0, cA2);
        BAR(); LGKM0();
        PHASE_MFMA(0, 1);
        BAR();
        // P3: a kk1 m4-7  (+ counted vmcnt)
#pragma unroll
        for (int m = 0; m < 4; ++m) aa[m] = *(const bf16x8*)(A01 + offA[4 + m]);
        STB(0, 0, cB2);
        BAR(); LGKM0();
        PHASE_MFMA(4, 1);
        VM6();
        BAR();

        // ---- odd tile (buf1) ----
        // P4
#pragma unroll
        for (int g = 0; g < 4; ++g) {
            bb[0][g] = *(const bf16x8*)(B1 + offB[g][0]);
            bb[1][g] = *(const bf16x8*)(B1 + offB[g][1]);
        }
#pragma unroll
        for (int m = 0; m < 4; ++m) aa[m] = *(const bf16x8*)(A10 + offA[m]);
        STA(0, 1, cA2);
        BAR(); LGKM0();
        PHASE_MFMA(0, 0);
        BAR();
        // P5
#pragma unroll
        for (int m = 0; m < 4; ++m) aa[m] = *(const bf16x8*)(A10 + offA[4 + m]);
        STB(1, 1, cB3);
        BAR(); LGKM0();
        PHASE_MFMA(4, 0);
        BAR();
        // P6
#pragma unroll
        for (int m = 0; m < 4; ++m) aa[m] = *(const bf16x8*)(A11 + offA[m]);
        STA(1, 0, cA3);
        BAR(); LGKM0();
        PHASE_MFMA(0, 1);
        BAR();
        // P7
#pragma unroll
        for (int m = 0; m < 4; ++m) aa[m] = *(const bf16x8*)(A11 + offA[4 + m]);
        STB(1, 0, cB3);
        BAR(); LGKM0();
        PHASE_MFMA(4, 1);
        VM6();
        BAR();
    }

    asm volatile("s_waitcnt vmcnt(0)" ::: "memory");

    // ---- fused LSTM epilogue: lane owns unit u across all 4 gates ----
    const int u = bc * 64 + wn * 16 + ln;
    const float bi  = bias[u];
    const float bfv = bias[UNITS + u];
    const float bg  = bias[2 * UNITS + u];
    const float bo  = bias[3 * UNITS + u];
#pragma unroll
    for (int m = 0; m < 8; ++m) {
        const int row0 = rb * 256 + wm * 128 + m * 16 + lk * 4;
#pragma unroll
        for (int r = 0; r < 4; ++r) {
            const size_t ic = (size_t)(row0 + r) * UNITS + u;
            float ig = sigmoid_f(acc[m][0][r] + bi);
            float fg = sigmoid_f(acc[m][1][r] + bfv);
            float gg = tanh_f(acc[m][2][r] + bg);
            float og = sigmoid_f(acc[m][3][r] + bo);
            float cn = fg * cstate[ic] + ig * gg;
            cstate[ic] = cn;
            hout[(size_t)(row0 + r) * HSTRIDE + u] = (__bf16)(og * tanh_f(cn));
        }
    }
#undef STA
#undef STB
}

// ---------------- final dense: [4096,1024] @ [1024,640] -> logits fp32 ----------------
__global__ void __launch_bounds__(256) dense_kernel(
    const __bf16* __restrict__ hin,
    const __bf16* __restrict__ Wt2p,
    float*        __restrict__ logits)
{
    __shared__ __bf16 As[128 * 64];
    __shared__ __bf16 Bs[128 * 64];

    const int tid  = threadIdx.x;
    const int wid  = tid >> 6;
    const int lane = tid & 63;
    const int ln   = lane & 15;
    const int lk   = lane >> 4;
    const int wm   = wid >> 1;
    const int wn   = wid & 1;
    const int rb   = blockIdx.x;
    const int nb   = blockIdx.y;

    floatx4 acc[4][4];
#pragma unroll
    for (int m = 0; m < 4; ++m)
#pragma unroll
        for (int g = 0; g < 4; ++g)
            acc[m][g] = (floatx4){0.f, 0.f, 0.f, 0.f};

    int s_row[4], s_kgd[4];
#pragma unroll
    for (int q = 0; q < 4; ++q) {
        int flat = q * 256 + tid;
        int row  = flat >> 3;
        s_row[q] = row;
        s_kgd[q] = (flat & 7) ^ (row & 7);
    }

    for (int kt = 0; kt < 16; ++kt) {
        __syncthreads();
#pragma unroll
        for (int q = 0; q < 4; ++q) {
            const int row = s_row[q], kgd = s_kgd[q];
            const __bf16* gp = hin + (size_t)(rb * 128 + row) * HSTRIDE + kt * 64 + kgd * 8;
            GLDS(gp, As + (size_t)(q * 256 + (wid << 6)) * 8);
        }
#pragma unroll
        for (int q = 0; q < 4; ++q) {
            const int n = s_row[q], kgd = s_kgd[q];
            const __bf16* gp = Wt2p + ((size_t)(nb * 128 + n) << 10) + kt * 64 + kgd * 8;
            GLDS(gp, Bs + (size_t)(q * 256 + (wid << 6)) * 8);
        }
        __syncthreads();
#pragma unroll
        for (int kk = 0; kk < 2; ++kk) {
            const int kg = kk * 4 + lk;
            bf16x8 a[4], b[4];
#pragma unroll
            for (int m = 0; m < 4; ++m) {
                int row  = wm * 64 + m * 16 + ln;
                int ccol = (kg ^ (row & 7)) * 8;
                a[m] = *(const bf16x8*)(As + row * 64 + ccol);
            }
#pragma unroll
            for (int g = 0; g < 4; ++g) {
                int n    = g * 32 + wn * 16 + ln;
                int ccol = (kg ^ (n & 7)) * 8;
                b[g] = *(const bf16x8*)(Bs + n * 64 + ccol);
            }
#pragma unroll
            for (int m = 0; m < 4; ++m)
#pragma unroll
                for (int g = 0; g < 4; ++g)
                    acc[m][g] = MFMA(a[m], b[g], acc[m][g], 0, 0, 0);
        }
    }

#pragma unroll
    for (int m = 0; m < 4; ++m) {
        const int row0 = rb * 128 + wm * 64 + m * 16 + lk * 4;
#pragma unroll
        for (int g = 0; g < 4; ++g) {
            const int n = nb * 128 + g * 32 + wn * 16 + ln;
#pragma unroll
            for (int r = 0; r < 4; ++r)
                logits[(size_t)(row0 + r) * NPAD + n] = acc[m][g][r];
        }
    }
}

// ---------------- row softmax over 578 cols (+b2) ----------------
__global__ void __launch_bounds__(256) softmax_kernel(
    const float* __restrict__ logits,
    const float* __restrict__ b2,
    float* __restrict__ out)
{
    const int row = blockIdx.x;
    const int tid = threadIdx.x;
    __shared__ float red[8];

    float z[3];
    float lmax = -1e30f;
#pragma unroll
    for (int j = 0; j < 3; ++j) {
        int col = tid + j * 256;
        if (col < VOCAB) {
            z[j] = logits[(size_t)row * NPAD + col] + b2[col];
            lmax = fmaxf(lmax, z[j]);
        } else z[j] = -1e30f;
    }
    for (int off = 32; off > 0; off >>= 1) lmax = fmaxf(lmax, __shfl_xor(lmax, off));
    if ((tid & 63) == 0) red[tid >> 6] = lmax;
    __syncthreads();
    lmax = fmaxf(fmaxf(red[0], red[1]), fmaxf(red[2], red[3]));
    __syncthreads();

    float lsum = 0.f;
#pragma unroll
    for (int j = 0; j < 3; ++j) {
        int col = tid + j * 256;
        if (col < VOCAB) { z[j] = __expf(z[j] - lmax); lsum += z[j]; }
    }
    for (int off = 32; off > 0; off >>= 1) lsum += __shfl_xor(lsum, off);
    if ((tid & 63) == 0) red[tid >> 6] = lsum;
    __syncthreads();
    lsum = red[0] + red[1] + red[2] + red[3];
    float inv = 1.f / lsum;
#pragma unroll
    for (int j = 0; j < 3; ++j) {
        int col = tid + j * 256;
        if (col < VOCAB) out[(size_t)row * VOCAB + col] = z[j] * inv;
    }
}

// ---------------- launch ----------------
extern "C" void kernel_launch(void* const* d_in, const int* in_sizes, int n_in,
                              void* d_out, int out_size, void* d_ws, size_t ws_size,
                              hipStream_t stream)
{
    const float* x    = (const float*)d_in[0];
    const float* kern = (const float*)d_in[1];
    const float* reck = (const float*)d_in[2];
    const float* bias = (const float*)d_in[3];
    const float* w2   = (const float*)d_in[4];
    const float* b2   = (const float*)d_in[5];
    float* out = (float*)d_out;

    char* ws = (char*)d_ws;
    size_t off = 0;
    auto alloc = [&](size_t bytes) {
        char* p = ws + off;
        off += (bytes + 255) & ~(size_t)255;
        return p;
    };
    __bf16* Wtp    = (__bf16*)alloc((size_t)4096 * KPAD * 2);
    __bf16* Wt2p   = (__bf16*)alloc((size_t)NPAD * 1024 * 2);
    __bf16* xbf    = (__bf16*)alloc((size_t)BATCH * SEQ * FEAT * 2);
    __bf16* h0     = (__bf16*)alloc((size_t)BATCH * HSTRIDE * 2);
    __bf16* h1     = (__bf16*)alloc((size_t)BATCH * HSTRIDE * 2);
    float*  cst    = (float*)alloc((size_t)BATCH * UNITS * 4);
    float*  logits = (float*)alloc((size_t)BATCH * NPAD * 4);
    if (off > ws_size) return;  // loud failure: output stays zero

    (void)hipMemsetAsync(h0, 0, (size_t)BATCH * HSTRIDE * 2, stream);
    (void)hipMemsetAsync(h1, 0, (size_t)BATCH * HSTRIDE * 2, stream);
    (void)hipMemsetAsync(cst, 0, (size_t)BATCH * UNITS * 4, stream);

    convert_x_kernel<<<(BATCH * SEQ * FEAT / 4 + 255) / 256, 256, 0, stream>>>(x, xbf);
    convert_weights_kernel<<<(4096 * KPAD + 255) / 256, 256, 0, stream>>>(kern, reck, Wtp);
    convert_w2_kernel<<<(NPAD * 1024 + 255) / 256, 256, 0, stream>>>(w2, Wt2p);

    __bf16* hin = h0; __bf16* hout = h1;
    for (int t = 0; t < SEQ; ++t) {
        lstm_step_kernel<<<dim3(16, 16), 512, 0, stream>>>(xbf, Wtp, bias, hin, hout, cst, t);
        __bf16* tmp = hin; hin = hout; hout = tmp;
    }

    dense_kernel<<<dim3(32, 5), 256, 0, stream>>>(hin, Wt2p, logits);
    softmax_kernel<<<BATCH, 256, 0, stream>>>(logits, b2, out);
}